// Round 8
// baseline (141.657 us; speedup 1.0000x reference)
//
#include <hip/hip_runtime.h>

// FullScan via bf16 MFMA 32x32x16, full-M packing.
// out[k,t] = sum_{d<16,w<64} x[d,t+w]*P[k,d,w], K=8, L=1e6.
// M=32 rows = (k, tap-group g): row m = k + 8g (g covers taps [16g,16g+16)).
//   D_g[k](s) = sum_{c<16,d} P[k,d,16g+c] x[d,s+c]
//   out[k,t]  = sum_g D_g[k](t + 16g)
// C/D: col=lane&31, row=(reg&3)+8*(reg>>2)+4h => reg kk+4g = D_g[kk+4h](n).
// R12: dual attack after 4 nulls (R9 swizzle, R10 occupancy, R6/R11 B-depth):
//  (1) staging MLP: load-all-then-pack — all 20 float4 (80 VGPR) in flight
//      before first pack/ds_write; exposures 3->1, in-flight 8KB->20KB/wave.
//      Theory: chip-wide fetch is latency*MLP-capped at ~1.25 TB/s (hard
//      fact: 68MB/55us); R8's load-widening was the only win so far.
//  (2) MFMA chain split: even chunks->acc0, odd->acc1 (interleaved issue),
//      summed pre-epilogue. Breaks the 16-deep dependent accumulate chain
//      that no B-read pipelining could fix (explains R6/R11 nulls).
//  Regs ~150 -> 3 waves/SIMD, launch_bounds(256,3). Geometry/swizzle/
//  epilogue R11-identical.

constexpr int D    = 16;
constexpr int L    = 1000000;
constexpr int W    = 64;
constexpr int K    = 8;
constexpr int PADL = 31;
constexpr int NMID = L - W + 1;          // 999937
constexpr int TPB  = 256;                // 4 waves
constexpr int OTW  = 8;                  // out 32-pos tiles per wave
constexpr int CTW  = OTW + 2;            // computed tiles per wave
constexpr int BLK_OUT = 4 * OTW * 32;    // 1024 positions per block
constexpr int XS   = 1104;               // staged positions (need 1103), 276 quads
constexpr int NQ   = XS / 4;             // 276 float4 quads per row
constexpr int NBLK = (NMID + BLK_OUT - 1) / BLK_OUT;   // 977
constexpr int NGRID = NBLK + K;          // +8 edge blocks

typedef __attribute__((ext_vector_type(8)))  short short8;
typedef __attribute__((ext_vector_type(16))) float floatx16;

__device__ __forceinline__ unsigned short f2bf(float f) {
    union { float f; unsigned u; } v; v.f = f;
    unsigned u = v.u + 0x7fff + ((v.u >> 16) & 1);   // RNE
    return (unsigned short)(u >> 16);
}

__device__ __forceinline__ unsigned long long pack4(float a, float b,
                                                    float c, float d) {
    return (unsigned long long)f2bf(a)
         | ((unsigned long long)f2bf(b) << 16)
         | ((unsigned long long)f2bf(c) << 32)
         | ((unsigned long long)f2bf(d) << 48);
}

__global__ __launch_bounds__(TPB, 3) void fullscan_mid(
    const float* __restrict__ x, const float* __restrict__ P,
    const unsigned short* __restrict__ afr, float* __restrict__ out)
{
    __shared__ __align__(16) unsigned short xs[XS * 16];   // 35328 B
    const int bid = blockIdx.x;
    const int tid = threadIdx.x;

    if (bid >= NBLK) {
        // Edge block: k = bid - NBLK, 63 outputs (fp32 exact).
        const int k = bid - NBLK;
        const int j = tid;
        if (j < PADL) {
            float acc = 0.0f;
            for (int m = 0; m <= 32 + j; ++m)
#pragma unroll
                for (int d = 0; d < D; ++d)
                    acc = fmaf(x[d * L + m], P[(k * D + d) * W + m], acc);
            out[k * L + j] = acc;
        } else if (j < 2 * PADL + 1) {
            const int jj = j - PADL;                  // 0..31
            float acc = 0.0f;
            for (int m = jj + 1; m < W; ++m)
#pragma unroll
                for (int d = 0; d < D; ++d)
                    acc = fmaf(x[d * L + (L - W) + m], P[(k * D + d) * W + m], acc);
            out[k * L + PADL + NMID + jj] = acc;
        }
        return;
    }

    const int s0   = bid * BLK_OUT;
    const int lane = tid & 63;
    const int wv   = tid >> 6;

    // Stage x: thread (pl, dq) owns 4 d-rows; float4 over position-quads.
    // LOAD-ALL-THEN-PACK: all 20 float4 issued before any pack/ds_write ->
    // one latency exposure, 20KB in flight per wave (was 8KB, 3 exposures).
    // Column-XOR swizzle on 16B units (write banks spread 4x, reads whole-row).
    {
        const int pl = tid & 63;
        const int dq = tid >> 6;            // d-quad 0..3
        if (s0 + XS <= L) {
            const float4* xq0 = (const float4*)(x + (4 * dq + 0) * L + s0);
            const float4* xq1 = (const float4*)(x + (4 * dq + 1) * L + s0);
            const float4* xq2 = (const float4*)(x + (4 * dq + 2) * L + s0);
            const float4* xq3 = (const float4*)(x + (4 * dq + 3) * L + s0);
            float4 v[5][4];
#pragma unroll
            for (int it = 0; it < 5; ++it) {
                const int q = it * 64 + pl;
                if (q < NQ) {            // folds to true for it<4
                    v[it][0] = xq0[q];
                    v[it][1] = xq1[q];
                    v[it][2] = xq2[q];
                    v[it][3] = xq3[q];
                }
            }
#pragma unroll
            for (int it = 0; it < 5; ++it) {
                const int q = it * 64 + pl;
                if (q < NQ) {
                    const int rot = q & 3;
                    unsigned short* base = &xs[q * 64 + dq * 4];
                    *(unsigned long long*)(base + (0 ^ rot) * 16) = pack4(v[it][0].x, v[it][1].x, v[it][2].x, v[it][3].x);
                    *(unsigned long long*)(base + (1 ^ rot) * 16) = pack4(v[it][0].y, v[it][1].y, v[it][2].y, v[it][3].y);
                    *(unsigned long long*)(base + (2 ^ rot) * 16) = pack4(v[it][0].z, v[it][1].z, v[it][2].z, v[it][3].z);
                    *(unsigned long long*)(base + (3 ^ rot) * 16) = pack4(v[it][0].w, v[it][1].w, v[it][2].w, v[it][3].w);
                }
            }
        } else {
            // Last mid block only: scalar path with bounds clamp.
            const float* xr0 = x + (4 * dq + 0) * L + s0;
            const float* xr1 = x + (4 * dq + 1) * L + s0;
            const float* xr2 = x + (4 * dq + 2) * L + s0;
            const float* xr3 = x + (4 * dq + 3) * L + s0;
#pragma unroll 1
            for (int b = 0; b < XS; b += 64) {
                const int pos = b + pl;
                if (pos < XS) {
                    const bool ok = (s0 + pos) < L;
                    const float v0 = ok ? xr0[pos] : 0.0f;
                    const float v1 = ok ? xr1[pos] : 0.0f;
                    const float v2 = ok ? xr2[pos] : 0.0f;
                    const float v3 = ok ? xr3[pos] : 0.0f;
                    const int idx = (pos * 16 + dq * 4) ^ (((pos >> 2) & 3) << 4);
                    *(unsigned long long*)&xs[idx] = pack4(v0, v1, v2, v3);
                }
            }
        }
    }

    // Resident A fragments loaded AFTER staging: latency hides under the
    // barrier wait for other waves; keeps staging-phase reg pressure low.
    short8 A[16];
#pragma unroll
    for (int c = 0; c < 16; ++c)
        A[c] = *(const short8*)(afr + (c * 64 + lane) * 8);

    __syncthreads();

    const int n  = lane & 31;
    const int h  = lane >> 5;
    const int hb = h * 8;
    const int wbase = wv * OTW;             // first local out-tile of this wave

    // Incremental cross-tile combine state (16 regs):
    //   at iter jj, emit tile jj-2: v = pendA + shfl(g3);
    //   then pendA = pendB + acc[kk+8] + shfl(g1); save pendB/prev4/prev12.
    float pendA[4], pendB[4], prev4[4], prev12[4];

#pragma unroll
    for (int jj = 0; jj < CTW; ++jj) {
        // Dual accumulator chains: even chunks -> acc0, odd -> acc1.
        // Interleaved issue makes adjacent MFMAs independent (breaks the
        // 16-deep dependent accumulate chain).
        floatx16 acc0, acc1;
#pragma unroll
        for (int r = 0; r < 16; ++r) { acc0[r] = 0.0f; acc1[r] = 0.0f; }
        const int p0 = (wbase + jj) * 32 + n;

        // Group-4 double-buffered B reads (kept from R11).
        short8 Bc[4], Bn[4];
#pragma unroll
        for (int u = 0; u < 4; ++u) {
            const int pos = p0 + u;
            Bc[u] = *(const short8*)&xs[(pos * 16 + hb) ^ (((pos >> 2) & 3) << 4)];
        }
        // group 0: prefetch group 1, mfma chunks 0..3
#pragma unroll
        for (int u = 0; u < 4; ++u) {
            const int pos = p0 + 4 + u;
            Bn[u] = *(const short8*)&xs[(pos * 16 + hb) ^ (((pos >> 2) & 3) << 4)];
        }
#pragma unroll
        for (int u = 0; u < 4; ++u) {
            if (u & 1) acc1 = __builtin_amdgcn_mfma_f32_32x32x16_bf16(A[u], Bc[u], acc1, 0, 0, 0);
            else       acc0 = __builtin_amdgcn_mfma_f32_32x32x16_bf16(A[u], Bc[u], acc0, 0, 0, 0);
        }
        // group 1: prefetch group 2, mfma chunks 4..7
#pragma unroll
        for (int u = 0; u < 4; ++u) {
            const int pos = p0 + 8 + u;
            Bc[u] = *(const short8*)&xs[(pos * 16 + hb) ^ (((pos >> 2) & 3) << 4)];
        }
#pragma unroll
        for (int u = 0; u < 4; ++u) {
            if (u & 1) acc1 = __builtin_amdgcn_mfma_f32_32x32x16_bf16(A[4 + u], Bn[u], acc1, 0, 0, 0);
            else       acc0 = __builtin_amdgcn_mfma_f32_32x32x16_bf16(A[4 + u], Bn[u], acc0, 0, 0, 0);
        }
        // group 2: prefetch group 3, mfma chunks 8..11
#pragma unroll
        for (int u = 0; u < 4; ++u) {
            const int pos = p0 + 12 + u;
            Bn[u] = *(const short8*)&xs[(pos * 16 + hb) ^ (((pos >> 2) & 3) << 4)];
        }
#pragma unroll
        for (int u = 0; u < 4; ++u) {
            if (u & 1) acc1 = __builtin_amdgcn_mfma_f32_32x32x16_bf16(A[8 + u], Bc[u], acc1, 0, 0, 0);
            else       acc0 = __builtin_amdgcn_mfma_f32_32x32x16_bf16(A[8 + u], Bc[u], acc0, 0, 0, 0);
        }
        // group 3: mfma chunks 12..15
#pragma unroll
        for (int u = 0; u < 4; ++u) {
            if (u & 1) acc1 = __builtin_amdgcn_mfma_f32_32x32x16_bf16(A[12 + u], Bn[u], acc1, 0, 0, 0);
            else       acc0 = __builtin_amdgcn_mfma_f32_32x32x16_bf16(A[12 + u], Bn[u], acc0, 0, 0, 0);
        }

        // Merge chains, then incremental epilogue (unchanged algebra).
        floatx16 acc;
#pragma unroll
        for (int r = 0; r < 16; ++r) acc[r] = acc0[r] + acc1[r];

        if (jj >= 2) {
            const int ot = jj - 2;
            const int t = s0 + (wbase + ot) * 32 + n;
#pragma unroll
            for (int kk = 0; kk < 4; ++kk) {
                const float g3t = (n >= 16) ? prev12[kk] : acc[kk + 12];
                const float v = pendA[kk] + __shfl_xor(g3t, 16, 64);
                if (t < NMID)
                    out[(kk + 4 * h) * L + PADL + t] = v;
            }
        }
        if (jj >= 1) {
#pragma unroll
            for (int kk = 0; kk < 4; ++kk) {
                const float g1t = (n >= 16) ? prev4[kk] : acc[kk + 4];
                pendA[kk] = pendB[kk] + acc[kk + 8] + __shfl_xor(g1t, 16, 64);
            }
        }
#pragma unroll
        for (int kk = 0; kk < 4; ++kk) {
            pendB[kk]  = acc[kk];
            prev4[kk]  = acc[kk + 4];
            prev12[kk] = acc[kk + 12];
        }
    }
}

// Prep: A-fragment table. afr[c][lane][j] = bf16(P[k, d, w]),
// m=lane&31, h=lane>>5, k=m&7, g=m>>3, d=8h+j, w=16g+c.
__global__ void fullscan_prep(const float* __restrict__ P,
                              unsigned short* __restrict__ afr)
{
    const int u = blockIdx.x * 256 + threadIdx.x;   // 32 blocks x 256 = 8192
    const int c = u >> 9, lane = (u >> 3) & 63, j = u & 7;
    const int m = lane & 31, h = lane >> 5;
    const int k = m & 7, g = m >> 3;
    const int d = 8 * h + j;
    const int w = 16 * g + c;
    afr[u] = f2bf(P[(k * D + d) * W + w]);
}

extern "C" void kernel_launch(void* const* d_in, const int* in_sizes, int n_in,
                              void* d_out, int out_size, void* d_ws, size_t ws_size,
                              hipStream_t stream)
{
    const float* x = (const float*)d_in[0];   // (D, L)
    const float* P = (const float*)d_in[1];   // (K, D, W)
    float* out = (float*)d_out;
    unsigned short* afr = (unsigned short*)d_ws;   // 16 KB

    hipLaunchKernelGGL(fullscan_prep, dim3(32), dim3(256), 0, stream, P, afr);
    hipLaunchKernelGGL(fullscan_mid, dim3(NGRID), dim3(TPB), 0, stream,
                       x, P, afr, out);
}

// Round 9
// 134.433 us; speedup vs baseline: 1.0537x; 1.0537x over previous
//
#include <hip/hip_runtime.h>

// FullScan via bf16 MFMA 32x32x16, full-M packing.
// out[k,t] = sum_{d<16,w<64} x[d,t+w]*P[k,d,w], K=8, L=1e6.
// M=32 rows = (k, tap-group g): row m = k + 8g (g covers taps [16g,16g+16)).
//   D_g[k](s) = sum_{c<16,d} P[k,d,16g+c] x[d,s+c]
//   out[k,t]  = sum_g D_g[k](t + 16g)
// C/D: col=lane&31, row=(reg&3)+8*(reg>>2)+4h => reg kk+4g = D_g[kk+4h](n).
// R13: BARRIER REMOVAL. Wave wv reads only xs[wv*256 .. wv*256+335) —
//      ranges nearly disjoint (64-pos halo). So: per-wave self-contained
//      staging (each wave stages its own 84 quads; halo staged twice with
//      identical values = benign), NO __syncthreads. Waves de-align ->
//      one wave's MFMA overlaps SIMD-mates' fetches (chip-wide fetch and
//      compute phases no longer alternate); barrier vm/lgkm drain gone.
//      Theory: 6 within-phase ILP experiments all null at ~55us; the
//      aligned stage->barrier->compute structure was the invariant.
//      Compute loop / swizzle / epilogue / regs = R11 verbatim (no spills:
//      R12's v[5][4]+dual-acc spilled, WRITE 32->52MB, reverted).

constexpr int D    = 16;
constexpr int L    = 1000000;
constexpr int W    = 64;
constexpr int K    = 8;
constexpr int PADL = 31;
constexpr int NMID = L - W + 1;          // 999937
constexpr int TPB  = 256;                // 4 waves
constexpr int OTW  = 8;                  // out 32-pos tiles per wave
constexpr int CTW  = OTW + 2;            // computed tiles per wave
constexpr int BLK_OUT = 4 * OTW * 32;    // 1024 positions per block
constexpr int XS   = 1104;               // staged positions (need 1103), 276 quads
constexpr int NQ   = XS / 4;             // 276 float4 quads per row
constexpr int QPW  = 84;                 // quads per wave (335 pos -> 84 quads)
constexpr int NBLK = (NMID + BLK_OUT - 1) / BLK_OUT;   // 977
constexpr int NGRID = NBLK + K;          // +8 edge blocks

typedef __attribute__((ext_vector_type(8)))  short short8;
typedef __attribute__((ext_vector_type(16))) float floatx16;

__device__ __forceinline__ unsigned short f2bf(float f) {
    union { float f; unsigned u; } v; v.f = f;
    unsigned u = v.u + 0x7fff + ((v.u >> 16) & 1);   // RNE
    return (unsigned short)(u >> 16);
}

__device__ __forceinline__ unsigned long long pack4(float a, float b,
                                                    float c, float d) {
    return (unsigned long long)f2bf(a)
         | ((unsigned long long)f2bf(b) << 16)
         | ((unsigned long long)f2bf(c) << 32)
         | ((unsigned long long)f2bf(d) << 48);
}

__global__ __launch_bounds__(TPB, 3) void fullscan_mid(
    const float* __restrict__ x, const float* __restrict__ P,
    const unsigned short* __restrict__ afr, float* __restrict__ out)
{
    __shared__ __align__(16) unsigned short xs[XS * 16];   // 35328 B
    const int bid = blockIdx.x;
    const int tid = threadIdx.x;

    if (bid >= NBLK) {
        // Edge block: k = bid - NBLK, 63 outputs (fp32 exact).
        const int k = bid - NBLK;
        const int j = tid;
        if (j < PADL) {
            float acc = 0.0f;
            for (int m = 0; m <= 32 + j; ++m)
#pragma unroll
                for (int d = 0; d < D; ++d)
                    acc = fmaf(x[d * L + m], P[(k * D + d) * W + m], acc);
            out[k * L + j] = acc;
        } else if (j < 2 * PADL + 1) {
            const int jj = j - PADL;                  // 0..31
            float acc = 0.0f;
            for (int m = jj + 1; m < W; ++m)
#pragma unroll
                for (int d = 0; d < D; ++d)
                    acc = fmaf(x[d * L + (L - W) + m], P[(k * D + d) * W + m], acc);
            out[k * L + PADL + NMID + jj] = acc;
        }
        return;
    }

    const int s0   = bid * BLK_OUT;
    const int lane = tid & 63;
    const int wv   = tid >> 6;

    // Per-wave self-contained staging: wave wv stages quads
    // [wv*64, wv*64+QPW) — everything its own tiles will read. Halo quads
    // are staged by two waves with identical values (benign double-write).
    // Lane mapping: pq = lane&15 (16 consecutive quads -> coalesced 256B
    // per d-row segment), dqw = lane>>4 (d-quad).
    // Column-XOR swizzle: 16B unit (pos=4q+j, dq) at slot (j ^ (q&3)).
    {
        const int pq  = lane & 15;
        const int dqw = lane >> 4;          // d-quad 0..3
        if (s0 + XS <= L) {
            const float4* xq0 = (const float4*)(x + (4 * dqw + 0) * L + s0);
            const float4* xq1 = (const float4*)(x + (4 * dqw + 1) * L + s0);
            const float4* xq2 = (const float4*)(x + (4 * dqw + 2) * L + s0);
            const float4* xq3 = (const float4*)(x + (4 * dqw + 3) * L + s0);
#pragma unroll 2
            for (int it = 0; it < 6; ++it) {
                const int qrel = it * 16 + pq;
                if (qrel < QPW) {
                    const int q = wv * 64 + qrel;       // < NQ by construction
                    const float4 v0 = xq0[q];
                    const float4 v1 = xq1[q];
                    const float4 v2 = xq2[q];
                    const float4 v3 = xq3[q];
                    const int rot = q & 3;
                    unsigned short* base = &xs[q * 64 + dqw * 4];
                    *(unsigned long long*)(base + (0 ^ rot) * 16) = pack4(v0.x, v1.x, v2.x, v3.x);
                    *(unsigned long long*)(base + (1 ^ rot) * 16) = pack4(v0.y, v1.y, v2.y, v3.y);
                    *(unsigned long long*)(base + (2 ^ rot) * 16) = pack4(v0.z, v1.z, v2.z, v3.z);
                    *(unsigned long long*)(base + (3 ^ rot) * 16) = pack4(v0.w, v1.w, v2.w, v3.w);
                }
            }
        } else {
            // Last mid block only: element-wise clamp, same addressing.
            const float* xr0 = x + (4 * dqw + 0) * L + s0;
            const float* xr1 = x + (4 * dqw + 1) * L + s0;
            const float* xr2 = x + (4 * dqw + 2) * L + s0;
            const float* xr3 = x + (4 * dqw + 3) * L + s0;
#pragma unroll 1
            for (int it = 0; it < 6; ++it) {
                const int qrel = it * 16 + pq;
                if (qrel < QPW) {
                    const int q = wv * 64 + qrel;
                    const int rot = q & 3;
                    unsigned short* base = &xs[q * 64 + dqw * 4];
#pragma unroll
                    for (int j = 0; j < 4; ++j) {
                        const int pos = 4 * q + j;
                        const bool ok = (s0 + pos) < L;
                        const float v0 = ok ? xr0[pos] : 0.0f;
                        const float v1 = ok ? xr1[pos] : 0.0f;
                        const float v2 = ok ? xr2[pos] : 0.0f;
                        const float v3 = ok ? xr3[pos] : 0.0f;
                        *(unsigned long long*)(base + (j ^ rot) * 16) =
                            pack4(v0, v1, v2, v3);
                    }
                }
            }
        }
    }

    // Resident A fragments (hot in L2; latency hides under staging waits).
    short8 A[16];
#pragma unroll
    for (int c = 0; c < 16; ++c)
        A[c] = *(const short8*)(afr + (c * 64 + lane) * 8);

    // NO __syncthreads: each wave reads only LDS it wrote itself; the
    // compiler inserts same-wave lgkmcnt/vmcnt waits before first read.

    const int n  = lane & 31;
    const int h  = lane >> 5;
    const int hb = h * 8;
    const int wbase = wv * OTW;             // first local out-tile of this wave

    // Incremental cross-tile combine state (16 regs):
    //   at iter jj, emit tile jj-2: v = pendA + shfl(g3);
    //   then pendA = pendB + acc[kk+8] + shfl(g1); save pendB/prev4/prev12.
    float pendA[4], pendB[4], prev4[4], prev12[4];

#pragma unroll
    for (int jj = 0; jj < CTW; ++jj) {
        floatx16 acc;
#pragma unroll
        for (int r = 0; r < 16; ++r) acc[r] = 0.0f;
        const int p0 = (wbase + jj) * 32 + n;

        // Group-4 double-buffered B reads: 4 ds_read_b128 issued per group,
        // consumed one full group later.
        short8 Bc[4], Bn[4];
#pragma unroll
        for (int u = 0; u < 4; ++u) {
            const int pos = p0 + u;
            Bc[u] = *(const short8*)&xs[(pos * 16 + hb) ^ (((pos >> 2) & 3) << 4)];
        }
        // group 0: prefetch group 1, mfma chunks 0..3
#pragma unroll
        for (int u = 0; u < 4; ++u) {
            const int pos = p0 + 4 + u;
            Bn[u] = *(const short8*)&xs[(pos * 16 + hb) ^ (((pos >> 2) & 3) << 4)];
        }
#pragma unroll
        for (int u = 0; u < 4; ++u)
            acc = __builtin_amdgcn_mfma_f32_32x32x16_bf16(A[u], Bc[u], acc, 0, 0, 0);
        // group 1: prefetch group 2, mfma chunks 4..7
#pragma unroll
        for (int u = 0; u < 4; ++u) {
            const int pos = p0 + 8 + u;
            Bc[u] = *(const short8*)&xs[(pos * 16 + hb) ^ (((pos >> 2) & 3) << 4)];
        }
#pragma unroll
        for (int u = 0; u < 4; ++u)
            acc = __builtin_amdgcn_mfma_f32_32x32x16_bf16(A[4 + u], Bn[u], acc, 0, 0, 0);
        // group 2: prefetch group 3, mfma chunks 8..11
#pragma unroll
        for (int u = 0; u < 4; ++u) {
            const int pos = p0 + 12 + u;
            Bn[u] = *(const short8*)&xs[(pos * 16 + hb) ^ (((pos >> 2) & 3) << 4)];
        }
#pragma unroll
        for (int u = 0; u < 4; ++u)
            acc = __builtin_amdgcn_mfma_f32_32x32x16_bf16(A[8 + u], Bc[u], acc, 0, 0, 0);
        // group 3: mfma chunks 12..15
#pragma unroll
        for (int u = 0; u < 4; ++u)
            acc = __builtin_amdgcn_mfma_f32_32x32x16_bf16(A[12 + u], Bn[u], acc, 0, 0, 0);

        if (jj >= 2) {
            const int ot = jj - 2;
            const int t = s0 + (wbase + ot) * 32 + n;
#pragma unroll
            for (int kk = 0; kk < 4; ++kk) {
                const float g3t = (n >= 16) ? prev12[kk] : acc[kk + 12];
                const float v = pendA[kk] + __shfl_xor(g3t, 16, 64);
                if (t < NMID)
                    out[(kk + 4 * h) * L + PADL + t] = v;
            }
        }
        if (jj >= 1) {
#pragma unroll
            for (int kk = 0; kk < 4; ++kk) {
                const float g1t = (n >= 16) ? prev4[kk] : acc[kk + 4];
                pendA[kk] = pendB[kk] + acc[kk + 8] + __shfl_xor(g1t, 16, 64);
            }
        }
#pragma unroll
        for (int kk = 0; kk < 4; ++kk) {
            pendB[kk]  = acc[kk];
            prev4[kk]  = acc[kk + 4];
            prev12[kk] = acc[kk + 12];
        }
    }
}

// Prep: A-fragment table. afr[c][lane][j] = bf16(P[k, d, w]),
// m=lane&31, h=lane>>5, k=m&7, g=m>>3, d=8h+j, w=16g+c.
__global__ void fullscan_prep(const float* __restrict__ P,
                              unsigned short* __restrict__ afr)
{
    const int u = blockIdx.x * 256 + threadIdx.x;   // 32 blocks x 256 = 8192
    const int c = u >> 9, lane = (u >> 3) & 63, j = u & 7;
    const int m = lane & 31, h = lane >> 5;
    const int k = m & 7, g = m >> 3;
    const int d = 8 * h + j;
    const int w = 16 * g + c;
    afr[u] = f2bf(P[(k * D + d) * W + w]);
}

extern "C" void kernel_launch(void* const* d_in, const int* in_sizes, int n_in,
                              void* d_out, int out_size, void* d_ws, size_t ws_size,
                              hipStream_t stream)
{
    const float* x = (const float*)d_in[0];   // (D, L)
    const float* P = (const float*)d_in[1];   // (K, D, W)
    float* out = (float*)d_out;
    unsigned short* afr = (unsigned short*)d_ws;   // 16 KB

    hipLaunchKernelGGL(fullscan_prep, dim3(32), dim3(256), 0, stream, P, afr);
    hipLaunchKernelGGL(fullscan_mid, dim3(NGRID), dim3(TPB), 0, stream,
                       x, P, afr, out);
}

// Round 10
// 131.787 us; speedup vs baseline: 1.0749x; 1.0201x over previous
//
#include <hip/hip_runtime.h>

// FullScan via bf16 MFMA 32x32x16, full-M packing.
// out[k,t] = sum_{d<16,w<64} x[d,t+w]*P[k,d,w], K=8, L=1e6.
// M=32 rows = (k, tap-group g): row m = k + 8g (g covers taps [16g,16g+16)).
//   D_g[k](s) = sum_{c<16,d} P[k,d,16g+c] x[d,s+c]
//   out[k,t]  = sum_g D_g[k](t + 16g)
// C/D: col=lane&31, row=(reg&3)+8*(reg>>2)+4h => reg kk+4g = D_g[kk+4h](n).
// R14: GRID/RESIDENCY QUANTIZATION. bounds(256,3) + 35KB LDS = exactly
//      3 blocks/CU = 768 slots; old grid 985 -> TWO serial generations
//      (768 + 217 on a 72%-idle chip). wall = 2*T_block; occupancy ~17%
//      = (3+0.85)/2 slots avg — this, not regs, explains the counter, and
//      explains 7 consecutive null ILP experiments (they shrank neither
//      generation count nor the co-resident straggler wait).
//      Fix: OTW 8->11 => NBLK 711, NGRID 719 <= 768 => ONE generation.
//      LDS 47.6KB (3x = 143 <= 160 OK). Compute/staging/epilogue = R11
//      verbatim (proven 55us, 64 VGPR, no spill).

constexpr int D    = 16;
constexpr int L    = 1000000;
constexpr int W    = 64;
constexpr int K    = 8;
constexpr int PADL = 31;
constexpr int NMID = L - W + 1;          // 999937
constexpr int TPB  = 256;                // 4 waves
constexpr int OTW  = 11;                 // out 32-pos tiles per wave
constexpr int CTW  = OTW + 2;            // computed tiles per wave
constexpr int BLK_OUT = 4 * OTW * 32;    // 1408 positions per block
constexpr int XS   = 1488;               // staged positions (need 1487), 372 quads
constexpr int NQ   = XS / 4;             // 372 float4 quads per row
constexpr int NBLK = (NMID + BLK_OUT - 1) / BLK_OUT;   // 711
constexpr int NGRID = NBLK + K;          // 719 <= 768 resident slots
constexpr int SIT  = (NQ + 63) / 64;     // 6 staging iterations

typedef __attribute__((ext_vector_type(8)))  short short8;
typedef __attribute__((ext_vector_type(16))) float floatx16;

__device__ __forceinline__ unsigned short f2bf(float f) {
    union { float f; unsigned u; } v; v.f = f;
    unsigned u = v.u + 0x7fff + ((v.u >> 16) & 1);   // RNE
    return (unsigned short)(u >> 16);
}

__device__ __forceinline__ unsigned long long pack4(float a, float b,
                                                    float c, float d) {
    return (unsigned long long)f2bf(a)
         | ((unsigned long long)f2bf(b) << 16)
         | ((unsigned long long)f2bf(c) << 32)
         | ((unsigned long long)f2bf(d) << 48);
}

__global__ __launch_bounds__(TPB, 3) void fullscan_mid(
    const float* __restrict__ x, const float* __restrict__ P,
    const unsigned short* __restrict__ afr, float* __restrict__ out)
{
    __shared__ __align__(16) unsigned short xs[XS * 16];   // 47616 B
    const int bid = blockIdx.x;
    const int tid = threadIdx.x;

    if (bid >= NBLK) {
        // Edge block: k = bid - NBLK, 63 outputs (fp32 exact).
        const int k = bid - NBLK;
        const int j = tid;
        if (j < PADL) {
            float acc = 0.0f;
            for (int m = 0; m <= 32 + j; ++m)
#pragma unroll
                for (int d = 0; d < D; ++d)
                    acc = fmaf(x[d * L + m], P[(k * D + d) * W + m], acc);
            out[k * L + j] = acc;
        } else if (j < 2 * PADL + 1) {
            const int jj = j - PADL;                  // 0..31
            float acc = 0.0f;
            for (int m = jj + 1; m < W; ++m)
#pragma unroll
                for (int d = 0; d < D; ++d)
                    acc = fmaf(x[d * L + (L - W) + m], P[(k * D + d) * W + m], acc);
            out[k * L + PADL + NMID + jj] = acc;
        }
        return;
    }

    const int s0   = bid * BLK_OUT;
    const int lane = tid & 63;
    const int wv   = tid >> 6;

    // Stage x: thread (pl, dq) owns 4 d-rows; float4 over position-quads.
    // Column-XOR swizzle: 16B unit for (pos=4q+j, half) stored at slot
    // (j ^ (q&3)) within the 128B row q -> write banks spread 4x.
    {
        const int pl = tid & 63;
        const int dq = tid >> 6;            // d-quad 0..3
        if (s0 + XS <= L) {
            const float4* xq0 = (const float4*)(x + (4 * dq + 0) * L + s0);
            const float4* xq1 = (const float4*)(x + (4 * dq + 1) * L + s0);
            const float4* xq2 = (const float4*)(x + (4 * dq + 2) * L + s0);
            const float4* xq3 = (const float4*)(x + (4 * dq + 3) * L + s0);
#pragma unroll 2
            for (int it = 0; it < SIT; ++it) {
                const int q = it * 64 + pl;
                if (q < NQ) {
                    const float4 v0 = xq0[q];
                    const float4 v1 = xq1[q];
                    const float4 v2 = xq2[q];
                    const float4 v3 = xq3[q];
                    const int rot = q & 3;
                    unsigned short* base = &xs[q * 64 + dq * 4];
                    *(unsigned long long*)(base + (0 ^ rot) * 16) = pack4(v0.x, v1.x, v2.x, v3.x);
                    *(unsigned long long*)(base + (1 ^ rot) * 16) = pack4(v0.y, v1.y, v2.y, v3.y);
                    *(unsigned long long*)(base + (2 ^ rot) * 16) = pack4(v0.z, v1.z, v2.z, v3.z);
                    *(unsigned long long*)(base + (3 ^ rot) * 16) = pack4(v0.w, v1.w, v2.w, v3.w);
                }
            }
        } else {
            // Last mid block only: scalar path with bounds clamp.
            const float* xr0 = x + (4 * dq + 0) * L + s0;
            const float* xr1 = x + (4 * dq + 1) * L + s0;
            const float* xr2 = x + (4 * dq + 2) * L + s0;
            const float* xr3 = x + (4 * dq + 3) * L + s0;
#pragma unroll 1
            for (int b = 0; b < XS; b += 64) {
                const int pos = b + pl;
                if (pos < XS) {
                    const bool ok = (s0 + pos) < L;
                    const float v0 = ok ? xr0[pos] : 0.0f;
                    const float v1 = ok ? xr1[pos] : 0.0f;
                    const float v2 = ok ? xr2[pos] : 0.0f;
                    const float v3 = ok ? xr3[pos] : 0.0f;
                    const int idx = (pos * 16 + dq * 4) ^ (((pos >> 2) & 3) << 4);
                    *(unsigned long long*)&xs[idx] = pack4(v0, v1, v2, v3);
                }
            }
        }
    }

    // Resident A fragments loaded AFTER staging: latency hides under the
    // barrier wait for other waves; keeps staging-phase reg pressure low.
    short8 A[16];
#pragma unroll
    for (int c = 0; c < 16; ++c)
        A[c] = *(const short8*)(afr + (c * 64 + lane) * 8);

    __syncthreads();

    const int n  = lane & 31;
    const int h  = lane >> 5;
    const int hb = h * 8;
    const int wbase = wv * OTW;             // first local out-tile of this wave

    // Incremental cross-tile combine state (16 regs):
    //   at iter jj, emit tile jj-2: v = pendA + shfl(g3);
    //   then pendA = pendB + acc[kk+8] + shfl(g1); save pendB/prev4/prev12.
    float pendA[4], pendB[4], prev4[4], prev12[4];

#pragma unroll
    for (int jj = 0; jj < CTW; ++jj) {
        floatx16 acc;
#pragma unroll
        for (int r = 0; r < 16; ++r) acc[r] = 0.0f;
        const int p0 = (wbase + jj) * 32 + n;

        // Group-4 double-buffered B reads: 4 ds_read_b128 issued per group,
        // consumed one full group later.
        short8 Bc[4], Bn[4];
#pragma unroll
        for (int u = 0; u < 4; ++u) {
            const int pos = p0 + u;
            Bc[u] = *(const short8*)&xs[(pos * 16 + hb) ^ (((pos >> 2) & 3) << 4)];
        }
        // group 0: prefetch group 1, mfma chunks 0..3
#pragma unroll
        for (int u = 0; u < 4; ++u) {
            const int pos = p0 + 4 + u;
            Bn[u] = *(const short8*)&xs[(pos * 16 + hb) ^ (((pos >> 2) & 3) << 4)];
        }
#pragma unroll
        for (int u = 0; u < 4; ++u)
            acc = __builtin_amdgcn_mfma_f32_32x32x16_bf16(A[u], Bc[u], acc, 0, 0, 0);
        // group 1: prefetch group 2, mfma chunks 4..7
#pragma unroll
        for (int u = 0; u < 4; ++u) {
            const int pos = p0 + 8 + u;
            Bc[u] = *(const short8*)&xs[(pos * 16 + hb) ^ (((pos >> 2) & 3) << 4)];
        }
#pragma unroll
        for (int u = 0; u < 4; ++u)
            acc = __builtin_amdgcn_mfma_f32_32x32x16_bf16(A[4 + u], Bn[u], acc, 0, 0, 0);
        // group 2: prefetch group 3, mfma chunks 8..11
#pragma unroll
        for (int u = 0; u < 4; ++u) {
            const int pos = p0 + 12 + u;
            Bn[u] = *(const short8*)&xs[(pos * 16 + hb) ^ (((pos >> 2) & 3) << 4)];
        }
#pragma unroll
        for (int u = 0; u < 4; ++u)
            acc = __builtin_amdgcn_mfma_f32_32x32x16_bf16(A[8 + u], Bc[u], acc, 0, 0, 0);
        // group 3: mfma chunks 12..15
#pragma unroll
        for (int u = 0; u < 4; ++u)
            acc = __builtin_amdgcn_mfma_f32_32x32x16_bf16(A[12 + u], Bn[u], acc, 0, 0, 0);

        if (jj >= 2) {
            const int ot = jj - 2;
            const int t = s0 + (wbase + ot) * 32 + n;
#pragma unroll
            for (int kk = 0; kk < 4; ++kk) {
                const float g3t = (n >= 16) ? prev12[kk] : acc[kk + 12];
                const float v = pendA[kk] + __shfl_xor(g3t, 16, 64);
                if (t < NMID)
                    out[(kk + 4 * h) * L + PADL + t] = v;
            }
        }
        if (jj >= 1) {
#pragma unroll
            for (int kk = 0; kk < 4; ++kk) {
                const float g1t = (n >= 16) ? prev4[kk] : acc[kk + 4];
                pendA[kk] = pendB[kk] + acc[kk + 8] + __shfl_xor(g1t, 16, 64);
            }
        }
#pragma unroll
        for (int kk = 0; kk < 4; ++kk) {
            pendB[kk]  = acc[kk];
            prev4[kk]  = acc[kk + 4];
            prev12[kk] = acc[kk + 12];
        }
    }
}

// Prep: A-fragment table. afr[c][lane][j] = bf16(P[k, d, w]),
// m=lane&31, h=lane>>5, k=m&7, g=m>>3, d=8h+j, w=16g+c.
__global__ void fullscan_prep(const float* __restrict__ P,
                              unsigned short* __restrict__ afr)
{
    const int u = blockIdx.x * 256 + threadIdx.x;   // 32 blocks x 256 = 8192
    const int c = u >> 9, lane = (u >> 3) & 63, j = u & 7;
    const int m = lane & 31, h = lane >> 5;
    const int k = m & 7, g = m >> 3;
    const int d = 8 * h + j;
    const int w = 16 * g + c;
    afr[u] = f2bf(P[(k * D + d) * W + w]);
}

extern "C" void kernel_launch(void* const* d_in, const int* in_sizes, int n_in,
                              void* d_out, int out_size, void* d_ws, size_t ws_size,
                              hipStream_t stream)
{
    const float* x = (const float*)d_in[0];   // (D, L)
    const float* P = (const float*)d_in[1];   // (K, D, W)
    float* out = (float*)d_out;
    unsigned short* afr = (unsigned short*)d_ws;   // 16 KB

    hipLaunchKernelGGL(fullscan_prep, dim3(32), dim3(256), 0, stream, P, afr);
    hipLaunchKernelGGL(fullscan_mid, dim3(NGRID), dim3(TPB), 0, stream,
                       x, P, afr, out);
}